// Round 1
// baseline (1085.158 us; speedup 1.0000x reference)
//
#include <hip/hip_runtime.h>
#include <hip/hip_fp16.h>

typedef unsigned short u16;
typedef _Float16 f16;
typedef __attribute__((ext_vector_type(4))) u16 u16x4;
typedef __attribute__((ext_vector_type(8))) f16 f16x8;
typedef __attribute__((ext_vector_type(4))) float f32x4;

#define BATCH   2048
#define IN_DIM  376
#define KPAD0   384
#define HIDDEN  1024
#define OUT_DIM 17

// ---- workspace layout (bytes) ----
// z: 5*6*5 floats; x16: [2048][384] f16; acc16: 5x [2048][1024] f16;
// w0t: 20 mats [1024][384] f16 (i=1..5, o=0..3, transposed, k-padded w/ zeros);
// wht: 40 mats [1024][1024] f16 (10 edges x 4 ops, transposed).
#define WS_Z    0
#define WS_X16  1024
#define WS_ACC  (WS_X16 + (size_t)BATCH*KPAD0*2)         // 1,573,888
#define WS_W0T  (WS_ACC + (size_t)5*BATCH*HIDDEN*2)      // 22,545,408
#define WS_WHT  (WS_W0T + (size_t)20*HIDDEN*KPAD0*2)     // 38,274,048
// total ws used = WS_WHT + 40*HIDDEN*HIDDEN*2 = 122,160,128 (~117 MB)

// edge tables: h-edges (k=1..4 -> i=k+1..5) in prefix order
__device__ __constant__ int D_PREF[5] = {0, 0, 4, 7, 9};

// ---------------- z = softmax((log_alphas + eps)/tau) ----------------
__global__ void z_kernel(const float* __restrict__ la, const float* __restrict__ ep,
                         float* __restrict__ z) {
    int t = threadIdx.x;
    if (t >= 30) return;   // 5*6 (k,i) pairs
    float v[5]; float mx = -1e30f;
    #pragma unroll
    for (int o = 0; o < 5; ++o) { v[o] = la[t*5+o] + ep[t*5+o]; mx = fmaxf(mx, v[o]); }
    float s = 0.f;
    #pragma unroll
    for (int o = 0; o < 5; ++o) { v[o] = expf(v[o] - mx); s += v[o]; }
    float inv = 1.f / s;
    #pragma unroll
    for (int o = 0; o < 5; ++o) z[t*5+o] = v[o] * inv;
}

// ---------------- x (f32 [2048][376]) -> f16 [2048][384] (zero-pad) ----------------
__global__ void xcvt_kernel(const float* __restrict__ x, u16* __restrict__ x16) {
    int idx = blockIdx.x * 256 + threadIdx.x;     // < 2048*384
    int b = idx / KPAD0, c = idx % KPAD0;
    float v = (c < IN_DIM) ? x[(size_t)b*IN_DIM + c] : 0.f;
    f16 h = (f16)v;
    x16[idx] = __builtin_bit_cast(u16, h);
}

// ---------------- W0 slices -> transposed f16 [n=1024][k=384] ----------------
// grid: 20 mats * 6 ktiles * 16 ntiles = 1920 blocks, 256 thr
__global__ void wtrans0_kernel(const float* __restrict__ W0, u16* __restrict__ dst) {
    __shared__ u16 sT[64*68];
    int bid = blockIdx.x;
    int mat = bid / 96, rem = bid % 96;
    int kt = rem / 16, nt = rem % 16;
    int i = mat / 4 + 1, o = mat % 4;
    const float* src = W0 + (size_t)(i*5 + o) * IN_DIM * HIDDEN;
    int t = threadIdx.x;
    #pragma unroll
    for (int p = 0; p < 16; ++p) {
        int e = p*256 + t;
        int kr = e >> 6, nc = e & 63;
        int k = kt*64 + kr;
        float v = (k < IN_DIM) ? src[(size_t)k*HIDDEN + nt*64 + nc] : 0.f;
        f16 h = (f16)v;
        sT[nc*68 + kr] = __builtin_bit_cast(u16, h);
    }
    __syncthreads();
    u16* d = dst + (size_t)mat * HIDDEN * KPAD0;
    #pragma unroll
    for (int p = 0; p < 4; ++p) {
        int c = p*256 + t;
        int nc = c >> 4, k4 = (c & 15) * 4;
        u16x4 v;
        #pragma unroll
        for (int j = 0; j < 4; ++j) v[j] = sT[nc*68 + k4 + j];
        *(u16x4*)&d[(size_t)(nt*64 + nc)*KPAD0 + kt*64 + k4] = v;
    }
}

// ---------------- Wh used slices -> transposed f16 [1024][1024] ----------------
// grid: 40 mats * 16 ktiles * 16 ntiles = 10240 blocks
__global__ void wtransH_kernel(const float* __restrict__ Wh, u16* __restrict__ dst) {
    const int SK[10] = {1,1,1,1,2,2,2,3,3,4};
    const int SI[10] = {2,3,4,5,3,4,5,4,5,5};
    __shared__ u16 sT[64*68];
    int bid = blockIdx.x;
    int mat = bid >> 8, rem = bid & 255;
    int kt = rem / 16, nt = rem % 16;
    int e = mat / 4, o = mat % 4;
    int k_src = SK[e], i_src = SI[e];
    const float* src = Wh + (size_t)(((k_src-1)*6 + i_src)*5 + o) * HIDDEN * HIDDEN;
    int t = threadIdx.x;
    #pragma unroll
    for (int p = 0; p < 16; ++p) {
        int ee = p*256 + t;
        int kr = ee >> 6, nc = ee & 63;
        float v = src[(size_t)(kt*64 + kr)*HIDDEN + nt*64 + nc];
        f16 h = (f16)v;
        sT[nc*68 + kr] = __builtin_bit_cast(u16, h);
    }
    __syncthreads();
    u16* d = dst + (size_t)mat * HIDDEN * HIDDEN;
    #pragma unroll
    for (int p = 0; p < 4; ++p) {
        int c = p*256 + t;
        int nc = c >> 4, k4 = (c & 15) * 4;
        u16x4 v;
        #pragma unroll
        for (int j = 0; j < 4; ++j) v[j] = sT[nc*68 + k4 + j];
        *(u16x4*)&d[(size_t)(nt*64 + nc)*HIDDEN + kt*64 + k4] = v;
    }
}

// ---------------- one DAG step: acc_i = sum_k sum_o z*act_o(in_k @ W + b) ----------------
// block tile 64x64, 4 waves (each 64m x 16n), 4 fused op-accumulators.
__global__ __launch_bounds__(256)
void step_kernel(int stepi,
                 const u16* __restrict__ x16, u16* __restrict__ accb,
                 const u16* __restrict__ w0t, const u16* __restrict__ wht,
                 const float* __restrict__ b0, const float* __restrict__ bh,
                 const float* __restrict__ zws) {
    __shared__ u16 sA[64*36];
    __shared__ u16 sB[4][64*36];
    const int t = threadIdx.x;
    const int lane = t & 63, wid = t >> 6;
    const int l15 = lane & 15, lk = lane >> 4;
    const int m0 = blockIdx.x * 64;
    const int n0 = blockIdx.y * 64;
    const int colw = n0 + wid*16 + l15;

    f32x4 run[4] = {};   // running z-weighted mix, [mfrag]

    for (int k = 0; k < stepi; ++k) {
        const u16* Ap; int ldA, nks, ldW;
        const u16* Wt; const float* bias;
        if (k == 0) {
            Ap = x16; ldA = KPAD0; nks = KPAD0/32;
            Wt = w0t + (size_t)((stepi-1)*4) * HIDDEN * KPAD0; ldW = KPAD0;
            bias = b0 + (size_t)(stepi*5) * HIDDEN;
        } else {
            Ap = accb + (size_t)(k-1) * BATCH * HIDDEN; ldA = HIDDEN; nks = HIDDEN/32;
            int eidx = D_PREF[k] + (stepi - k - 1);
            Wt = wht + (size_t)(eidx*4) * HIDDEN * HIDDEN; ldW = HIDDEN;
            bias = bh + (size_t)(((k-1)*6 + stepi)*5) * HIDDEN;
        }
        const float* zp = zws + (k*6 + stepi)*5;

        f32x4 acc[4][4] = {};   // [mfrag][op]

        for (int kb = 0; kb < nks; ++kb) {
            const int koff = kb * 32;
            // stage A: 64 rows x 32 halves
            #pragma unroll
            for (int p = 0; p < 2; ++p) {
                int c = t + p*256;
                int row = c >> 3, c4 = (c & 7) * 4;
                u16x4 v = *(const u16x4*)&Ap[(size_t)(m0 + row)*ldA + koff + c4];
                *(u16x4*)&sA[row*36 + c4] = v;
            }
            // stage B: wave 'wid' stages op 'wid' (64 n-rows x 32 halves, pre-transposed)
            {
                const u16* Wop = Wt + (size_t)wid * HIDDEN * ldW;
                #pragma unroll
                for (int p = 0; p < 8; ++p) {
                    int c = lane + p*64;
                    int row = c >> 3, c4 = (c & 7) * 4;
                    u16x4 v = *(const u16x4*)&Wop[(size_t)(n0 + row)*ldW + koff + c4];
                    *(u16x4*)&sB[wid][row*36 + c4] = v;
                }
            }
            __syncthreads();
            union FA { f16x8 v; u16x4 h[2]; };
            FA af[4];
            #pragma unroll
            for (int f = 0; f < 4; ++f) {
                int off = (f*16 + l15)*36 + lk*8;
                af[f].h[0] = *(const u16x4*)&sA[off];
                af[f].h[1] = *(const u16x4*)&sA[off + 4];
            }
            #pragma unroll
            for (int o = 0; o < 4; ++o) {
                FA bf;
                int off = (wid*16 + l15)*36 + lk*8;
                bf.h[0] = *(const u16x4*)&sB[o][off];
                bf.h[1] = *(const u16x4*)&sB[o][off + 4];
                #pragma unroll
                for (int f = 0; f < 4; ++f)
                    acc[f][o] = __builtin_amdgcn_mfma_f32_16x16x32_f16(af[f].v, bf.v, acc[f][o], 0, 0, 0);
            }
            __syncthreads();
        }
        // epilogue: bias + activation + z-weighted accumulate
        #pragma unroll
        for (int o = 0; o < 4; ++o) {
            float zv = zp[o];
            float bv = bias[(size_t)o*HIDDEN + colw];
            #pragma unroll
            for (int f = 0; f < 4; ++f) {
                #pragma unroll
                for (int r = 0; r < 4; ++r) {
                    float pre = acc[f][o][r] + bv;
                    float a;
                    if      (o == 0) a = tanhf(pre);
                    else if (o == 1) a = fmaxf(pre, 0.f);
                    else if (o == 2) a = (pre > 0.f) ? pre : expm1f(pre);
                    else             a = (pre > 0.f) ? pre : 0.01f * pre;
                    run[f][r] += zv * a;
                }
            }
        }
    }
    // store acc_i as f16
    u16* accout = accb + (size_t)(stepi-1) * BATCH * HIDDEN;
    const int rb = m0 + lk*4;
    #pragma unroll
    for (int f = 0; f < 4; ++f) {
        #pragma unroll
        for (int r = 0; r < 4; ++r) {
            f16 h = (f16)run[f][r];
            accout[(size_t)(rb + f*16 + r)*HIDDEN + colw] = __builtin_bit_cast(u16, h);
        }
    }
}

// ---------------- out = tanh(acc5 @ Wout + bout) ----------------
// 16 rows per block; 16 lanes cooperate per row.
__global__ void out_kernel(const u16* __restrict__ acc5, const float* __restrict__ Wout,
                           const float* __restrict__ bout, float* __restrict__ out) {
    int t = threadIdx.x;
    int g = t & 15, rl = t >> 4;
    int row = blockIdx.x * 16 + rl;
    const f16* a = (const f16*)acc5 + (size_t)row * HIDDEN;
    float s[OUT_DIM] = {};
    for (int kk = 0; kk < HIDDEN/16; ++kk) {
        int kidx = kk*16 + g;
        float av = (float)a[kidx];
        const float* wr = Wout + (size_t)kidx * OUT_DIM;
        #pragma unroll
        for (int j = 0; j < OUT_DIM; ++j) s[j] += av * wr[j];
    }
    #pragma unroll
    for (int m = 1; m < 16; m <<= 1) {
        #pragma unroll
        for (int j = 0; j < OUT_DIM; ++j) s[j] += __shfl_xor(s[j], m, 64);
    }
    if (g == 0) {
        #pragma unroll
        for (int j = 0; j < OUT_DIM; ++j)
            out[(size_t)row*OUT_DIM + j] = tanhf(s[j] + bout[j]);   // MAX_OUTPUT = 1
    }
}

extern "C" void kernel_launch(void* const* d_in, const int* in_sizes, int n_in,
                              void* d_out, int out_size, void* d_ws, size_t ws_size,
                              hipStream_t stream) {
    const float* x    = (const float*)d_in[0];
    const float* W0   = (const float*)d_in[1];
    const float* b0   = (const float*)d_in[2];
    const float* Wh   = (const float*)d_in[3];
    const float* bh   = (const float*)d_in[4];
    const float* Wout = (const float*)d_in[5];
    const float* bout = (const float*)d_in[6];
    const float* la   = (const float*)d_in[7];
    const float* eps  = (const float*)d_in[8];
    float* out = (float*)d_out;

    char* ws = (char*)d_ws;
    float* zws = (float*)(ws + WS_Z);
    u16* x16  = (u16*)(ws + WS_X16);
    u16* accb = (u16*)(ws + WS_ACC);
    u16* w0t  = (u16*)(ws + WS_W0T);
    u16* wht  = (u16*)(ws + WS_WHT);

    z_kernel<<<1, 32, 0, stream>>>(la, eps, zws);
    xcvt_kernel<<<(BATCH*KPAD0)/256, 256, 0, stream>>>(x, x16);
    wtrans0_kernel<<<1920, 256, 0, stream>>>(W0, w0t);
    wtransH_kernel<<<10240, 256, 0, stream>>>(Wh, wht);
    for (int i = 1; i <= 5; ++i)
        step_kernel<<<dim3(32, 16), 256, 0, stream>>>(i, x16, accb, w0t, wht, b0, bh, zws);
    out_kernel<<<BATCH/16, 256, 0, stream>>>(accb + (size_t)4*BATCH*HIDDEN, Wout, bout, out);
}

// Round 2
// 1044.555 us; speedup vs baseline: 1.0389x; 1.0389x over previous
//
#include <hip/hip_runtime.h>
#include <hip/hip_fp16.h>

typedef unsigned short u16;
typedef _Float16 f16;
typedef __attribute__((ext_vector_type(4))) u16 u16x4;
typedef __attribute__((ext_vector_type(8))) f16 f16x8;
typedef __attribute__((ext_vector_type(4))) float f32x4;

#define BATCH   2048
#define IN_DIM  376
#define KPAD0   384
#define HIDDEN  1024
#define OUT_DIM 17

// ---- workspace layout (bytes) ----
#define WS_Z     0
#define WS_X16   1024
#define WS_ACC16 (WS_X16 + (size_t)BATCH*KPAD0*2)            // 4 f16 bufs (steps 1..4)
#define WS_ACCF  (WS_ACC16 + (size_t)4*BATCH*HIDDEN*2)       // 5 f32 bufs
#define WS_W0T   (WS_ACCF + (size_t)5*BATCH*HIDDEN*4)
#define WS_WHT   (WS_W0T + (size_t)20*HIDDEN*KPAD0*2)
// end = WS_WHT + 40*HIDDEN*HIDDEN*2  (~153 MB)

__device__ __constant__ int D_PREF[5] = {0, 0, 4, 7, 9};

__device__ inline void gll16(const void* g, void* l) {
    __builtin_amdgcn_global_load_lds(
        (const __attribute__((address_space(1))) unsigned int*)g,
        (__attribute__((address_space(3))) unsigned int*)l, 16, 0, 0);
}

// ---------------- z = softmax((log_alphas + eps)/tau) ----------------
__global__ void z_kernel(const float* __restrict__ la, const float* __restrict__ ep,
                         float* __restrict__ z) {
    int t = threadIdx.x;
    if (t >= 30) return;
    float v[5]; float mx = -1e30f;
    #pragma unroll
    for (int o = 0; o < 5; ++o) { v[o] = la[t*5+o] + ep[t*5+o]; mx = fmaxf(mx, v[o]); }
    float s = 0.f;
    #pragma unroll
    for (int o = 0; o < 5; ++o) { v[o] = expf(v[o] - mx); s += v[o]; }
    float inv = 1.f / s;
    #pragma unroll
    for (int o = 0; o < 5; ++o) z[t*5+o] = v[o] * inv;
}

// ---------------- x f32 [2048][376] -> f16 [2048][384] zero-padded ----------------
__global__ void xcvt_kernel(const float* __restrict__ x, u16* __restrict__ x16) {
    int idx = blockIdx.x * 256 + threadIdx.x;
    int b = idx / KPAD0, c = idx % KPAD0;
    float v = (c < IN_DIM) ? x[(size_t)b*IN_DIM + c] : 0.f;
    f16 h = (f16)v;
    x16[idx] = __builtin_bit_cast(u16, h);
}

// ---------------- W0 slices -> transposed f16 [n=1024][k=384] ----------------
__global__ void wtrans0_kernel(const float* __restrict__ W0, u16* __restrict__ dst) {
    __shared__ u16 sT[64*68];
    int bid = blockIdx.x;
    int mat = bid / 96, rem = bid % 96;
    int kt = rem / 16, nt = rem % 16;
    int i = mat / 4 + 1, o = mat % 4;
    const float* src = W0 + (size_t)(i*5 + o) * IN_DIM * HIDDEN;
    int t = threadIdx.x;
    #pragma unroll
    for (int p = 0; p < 16; ++p) {
        int e = p*256 + t;
        int kr = e >> 6, nc = e & 63;
        int k = kt*64 + kr;
        float v = (k < IN_DIM) ? src[(size_t)k*HIDDEN + nt*64 + nc] : 0.f;
        f16 h = (f16)v;
        sT[nc*68 + kr] = __builtin_bit_cast(u16, h);
    }
    __syncthreads();
    u16* d = dst + (size_t)mat * HIDDEN * KPAD0;
    #pragma unroll
    for (int p = 0; p < 4; ++p) {
        int c = p*256 + t;
        int nc = c >> 4, k4 = (c & 15) * 4;
        u16x4 v;
        #pragma unroll
        for (int j = 0; j < 4; ++j) v[j] = sT[nc*68 + k4 + j];
        *(u16x4*)&d[(size_t)(nt*64 + nc)*KPAD0 + kt*64 + k4] = v;
    }
}

// ---------------- Wh used slices -> transposed f16 [1024][1024] ----------------
__global__ void wtransH_kernel(const float* __restrict__ Wh, u16* __restrict__ dst) {
    const int SK[10] = {1,1,1,1,2,2,2,3,3,4};
    const int SI[10] = {2,3,4,5,3,4,5,4,5,5};
    __shared__ u16 sT[64*68];
    int bid = blockIdx.x;
    int mat = bid >> 8, rem = bid & 255;
    int kt = rem / 16, nt = rem % 16;
    int e = mat / 4, o = mat % 4;
    const float* src = Wh + (size_t)(((SK[e]-1)*6 + SI[e])*5 + o) * HIDDEN * HIDDEN;
    int t = threadIdx.x;
    #pragma unroll
    for (int p = 0; p < 16; ++p) {
        int ee = p*256 + t;
        int kr = ee >> 6, nc = ee & 63;
        float v = src[(size_t)(kt*64 + kr)*HIDDEN + nt*64 + nc];
        f16 h = (f16)v;
        sT[nc*68 + kr] = __builtin_bit_cast(u16, h);
    }
    __syncthreads();
    u16* d = dst + (size_t)mat * HIDDEN * HIDDEN;
    #pragma unroll
    for (int p = 0; p < 4; ++p) {
        int c = p*256 + t;
        int nc = c >> 4, k4 = (c & 15) * 4;
        u16x4 v;
        #pragma unroll
        for (int j = 0; j < 4; ++j) v[j] = sT[nc*68 + k4 + j];
        *(u16x4*)&d[(size_t)(nt*64 + nc)*HIDDEN + kt*64 + k4] = v;
    }
}

// ---------------- zero the 5 f32 accumulator buffers ----------------
__global__ void zero_kernel(float* __restrict__ p) {
    int idx = blockIdx.x * 256 + threadIdx.x;
    *(f32x4*)&p[(size_t)idx*4] = (f32x4){0.f, 0.f, 0.f, 0.f};
}

// ---------------- f32 acc -> f16 for next step's A ----------------
__global__ void cvt_kernel(const float* __restrict__ src, u16* __restrict__ dst) {
    int idx = blockIdx.x * 256 + threadIdx.x;
    f32x4 v = *(const f32x4*)&src[(size_t)idx*4];
    u16x4 h;
    #pragma unroll
    for (int j = 0; j < 4; ++j) { f16 x = (f16)v[j]; h[j] = __builtin_bit_cast(u16, x); }
    *(u16x4*)&dst[(size_t)idx*4] = h;
}

// ---------------- one DAG edge: accf32_i += sum_o z*act_o(in_k @ W + b) ----------------
// block = 64m x 64n x 4 ops, one edge (blockIdx.z). BK=64.
// global_load_lds staging, XOR-swizzled LDS (chunk' = chunk ^ (row&7)), ds_read_b128.
__global__ __launch_bounds__(256)
void step_kernel(int stepi,
                 const u16* __restrict__ x16, const u16* __restrict__ acc16,
                 float* __restrict__ accf,
                 const u16* __restrict__ w0t, const u16* __restrict__ wht,
                 const float* __restrict__ b0, const float* __restrict__ bh,
                 const float* __restrict__ zws) {
    __shared__ alignas(16) u16 sA[64*64];
    __shared__ alignas(16) u16 sB[4][64*64];
    const int t = threadIdx.x;
    const int lane = t & 63, wid = t >> 6;
    const int l15 = lane & 15, lk = lane >> 4;
    const int m0 = blockIdx.x * 64;
    const int n0 = blockIdx.y * 64;
    const int k = blockIdx.z;   // edge source node

    const u16* Ap; int ldA, nks;
    const u16* Wt; int ldW;
    const float* bias;
    if (k == 0) {
        Ap = x16; ldA = KPAD0; nks = KPAD0/64;
        Wt = w0t + (size_t)((stepi-1)*4) * HIDDEN * KPAD0; ldW = KPAD0;
        bias = b0 + (size_t)(stepi*5) * HIDDEN;
    } else {
        Ap = acc16 + (size_t)(k-1) * BATCH * HIDDEN; ldA = HIDDEN; nks = HIDDEN/64;
        int eidx = D_PREF[k] + (stepi - k - 1);
        Wt = wht + (size_t)(eidx*4) * HIDDEN * HIDDEN; ldW = HIDDEN;
        bias = bh + (size_t)(((k-1)*6 + stepi)*5) * HIDDEN;
    }
    const float* zp = zws + (k*6 + stepi)*5;

    // staging lane geometry: within a 1KB chunk, lane L -> row_in_chunk = L>>3, slot c' = L&7,
    // fetch global chunk c = c' ^ (row&7)  (row&7 == L>>3 since chunks are 8 rows)
    const int srow = lane >> 3;
    const int sc   = (lane & 7) ^ srow;

    // A: wave wid stages chunks p = 2*wid, 2*wid+1 (rows wid*16+srow, wid*16+8+srow)
    const u16* aG0 = Ap + (size_t)(m0 + wid*16 + srow)     * ldA + sc*8;
    const u16* aG1 = Ap + (size_t)(m0 + wid*16 + 8 + srow) * ldA + sc*8;
    u16* aL0 = &sA[(wid*2)   * 512];
    u16* aL1 = &sA[(wid*2+1) * 512];
    // B: wave wid stages op 'wid', 8 chunks
    const u16* Wop = Wt + (size_t)wid * HIDDEN * ldW;
    const u16* bG[8];
    #pragma unroll
    for (int p = 0; p < 8; ++p)
        bG[p] = Wop + (size_t)(n0 + p*8 + srow) * ldW + sc*8;
    u16* bL = &sB[wid][0];

    f32x4 acc[4][4] = {};   // [mfrag][op]

    for (int kb = 0; kb < nks; ++kb) {
        const int koff = kb * 64;
        gll16(aG0 + koff, aL0);
        gll16(aG1 + koff, aL1);
        #pragma unroll
        for (int p = 0; p < 8; ++p)
            gll16(bG[p] + koff, bL + p*512);
        __syncthreads();
        #pragma unroll
        for (int kc = 0; kc < 2; ++kc) {
            f16x8 af[4], bf[4];
            #pragma unroll
            for (int f = 0; f < 4; ++f) {
                int row = f*16 + l15;
                int cc = (kc*4 + lk) ^ (row & 7);
                af[f] = *(const f16x8*)&sA[row*64 + cc*8];
            }
            #pragma unroll
            for (int o = 0; o < 4; ++o) {
                int row = wid*16 + l15;
                int cc = (kc*4 + lk) ^ (row & 7);
                bf[o] = *(const f16x8*)&sB[o][row*64 + cc*8];
            }
            #pragma unroll
            for (int o = 0; o < 4; ++o)
                #pragma unroll
                for (int f = 0; f < 4; ++f)
                    acc[f][o] = __builtin_amdgcn_mfma_f32_16x16x32_f16(af[f], bf[o], acc[f][o], 0, 0, 0);
        }
        __syncthreads();
    }

    // epilogue: bias + activation + z-mix (in-register), then one atomicAdd per element
    const int colw = n0 + wid*16 + l15;
    float outv[4][4] = {};
    #pragma unroll
    for (int o = 0; o < 4; ++o) {
        float zv = zp[o];
        float bv = bias[(size_t)o*HIDDEN + colw];
        #pragma unroll
        for (int f = 0; f < 4; ++f)
            #pragma unroll
            for (int r = 0; r < 4; ++r) {
                float pre = acc[f][o][r] + bv;
                float a;
                if      (o == 0) a = tanhf(pre);
                else if (o == 1) a = fmaxf(pre, 0.f);
                else if (o == 2) a = (pre > 0.f) ? pre : expm1f(pre);
                else             a = (pre > 0.f) ? pre : 0.01f * pre;
                outv[f][r] += zv * a;
            }
    }
    #pragma unroll
    for (int f = 0; f < 4; ++f)
        #pragma unroll
        for (int r = 0; r < 4; ++r)
            atomicAdd(&accf[(size_t)(m0 + f*16 + lk*4 + r)*HIDDEN + colw], outv[f][r]);
}

// ---------------- out = tanh(acc5_f32 @ Wout + bout) ----------------
__global__ void out_kernel(const float* __restrict__ acc5, const float* __restrict__ Wout,
                           const float* __restrict__ bout, float* __restrict__ out) {
    int t = threadIdx.x;
    int g = t & 15, rl = t >> 4;
    int row = blockIdx.x * 16 + rl;
    const float* a = acc5 + (size_t)row * HIDDEN;
    float s[OUT_DIM] = {};
    for (int kk = 0; kk < HIDDEN/16; ++kk) {
        int kidx = kk*16 + g;
        float av = a[kidx];
        const float* wr = Wout + (size_t)kidx * OUT_DIM;
        #pragma unroll
        for (int j = 0; j < OUT_DIM; ++j) s[j] += av * wr[j];
    }
    #pragma unroll
    for (int m = 1; m < 16; m <<= 1) {
        #pragma unroll
        for (int j = 0; j < OUT_DIM; ++j) s[j] += __shfl_xor(s[j], m, 64);
    }
    if (g == 0) {
        #pragma unroll
        for (int j = 0; j < OUT_DIM; ++j)
            out[(size_t)row*OUT_DIM + j] = tanhf(s[j] + bout[j]);
    }
}

extern "C" void kernel_launch(void* const* d_in, const int* in_sizes, int n_in,
                              void* d_out, int out_size, void* d_ws, size_t ws_size,
                              hipStream_t stream) {
    const float* x    = (const float*)d_in[0];
    const float* W0   = (const float*)d_in[1];
    const float* b0   = (const float*)d_in[2];
    const float* Wh   = (const float*)d_in[3];
    const float* bh   = (const float*)d_in[4];
    const float* Wout = (const float*)d_in[5];
    const float* bout = (const float*)d_in[6];
    const float* la   = (const float*)d_in[7];
    const float* eps  = (const float*)d_in[8];
    float* out = (float*)d_out;

    char* ws = (char*)d_ws;
    float* zws  = (float*)(ws + WS_Z);
    u16* x16    = (u16*)(ws + WS_X16);
    u16* acc16  = (u16*)(ws + WS_ACC16);
    float* accf = (float*)(ws + WS_ACCF);
    u16* w0t    = (u16*)(ws + WS_W0T);
    u16* wht    = (u16*)(ws + WS_WHT);

    z_kernel<<<1, 32, 0, stream>>>(la, eps, zws);
    xcvt_kernel<<<(BATCH*KPAD0)/256, 256, 0, stream>>>(x, x16);
    wtrans0_kernel<<<1920, 256, 0, stream>>>(W0, w0t);
    wtransH_kernel<<<10240, 256, 0, stream>>>(Wh, wht);
    zero_kernel<<<(5*BATCH*HIDDEN)/(4*256), 256, 0, stream>>>(accf);

    for (int i = 1; i <= 5; ++i) {
        float* accf_i = accf + (size_t)(i-1)*BATCH*HIDDEN;
        step_kernel<<<dim3(32, 16, i), 256, 0, stream>>>(
            i, x16, acc16, accf_i, w0t, wht, b0, bh, zws);
        if (i < 5)
            cvt_kernel<<<(BATCH*HIDDEN)/(4*256), 256, 0, stream>>>(
                accf_i, acc16 + (size_t)(i-1)*BATCH*HIDDEN);
    }
    out_kernel<<<BATCH/16, 256, 0, stream>>>(accf + (size_t)4*BATCH*HIDDEN, Wout, bout, out);
}

// Round 3
// 1029.430 us; speedup vs baseline: 1.0541x; 1.0147x over previous
//
#include <hip/hip_runtime.h>
#include <hip/hip_fp16.h>

typedef unsigned short u16;
typedef _Float16 f16;
typedef __attribute__((ext_vector_type(4))) u16 u16x4;
typedef __attribute__((ext_vector_type(8))) f16 f16x8;
typedef __attribute__((ext_vector_type(4))) float f32x4;

#define BATCH   2048
#define IN_DIM  376
#define KPAD0   384
#define HIDDEN  1024
#define OUT_DIM 17

// ---- workspace layout (bytes) ----
#define WS_Z     0
#define WS_X16   1024
#define WS_ACC16 (WS_X16 + (size_t)BATCH*KPAD0*2)            // 4 f16 bufs (steps 1..4)
#define WS_ACCF  (WS_ACC16 + (size_t)4*BATCH*HIDDEN*2)       // 5 f32 bufs
#define WS_W0T   (WS_ACCF + (size_t)5*BATCH*HIDDEN*4)
#define WS_WHT   (WS_W0T + (size_t)20*HIDDEN*KPAD0*2)

__device__ __constant__ int D_PREF[5] = {0, 0, 4, 7, 9};

__device__ inline void gll16(const void* g, void* l) {
    __builtin_amdgcn_global_load_lds(
        (const __attribute__((address_space(1))) unsigned int*)g,
        (__attribute__((address_space(3))) unsigned int*)l, 16, 0, 0);
}

// ---------------- z = softmax((log_alphas + eps)/tau) ----------------
__global__ void z_kernel(const float* __restrict__ la, const float* __restrict__ ep,
                         float* __restrict__ z) {
    int t = threadIdx.x;
    if (t >= 30) return;
    float v[5]; float mx = -1e30f;
    #pragma unroll
    for (int o = 0; o < 5; ++o) { v[o] = la[t*5+o] + ep[t*5+o]; mx = fmaxf(mx, v[o]); }
    float s = 0.f;
    #pragma unroll
    for (int o = 0; o < 5; ++o) { v[o] = expf(v[o] - mx); s += v[o]; }
    float inv = 1.f / s;
    #pragma unroll
    for (int o = 0; o < 5; ++o) z[t*5+o] = v[o] * inv;
}

// ---------------- x f32 [2048][376] -> f16 [2048][384] zero-padded ----------------
__global__ void xcvt_kernel(const float* __restrict__ x, u16* __restrict__ x16) {
    int idx = blockIdx.x * 256 + threadIdx.x;
    int b = idx / KPAD0, c = idx % KPAD0;
    float v = (c < IN_DIM) ? x[(size_t)b*IN_DIM + c] : 0.f;
    f16 h = (f16)v;
    x16[idx] = __builtin_bit_cast(u16, h);
}

// ---------------- W0 slices -> transposed f16 [n=1024][k=384] ----------------
__global__ void wtrans0_kernel(const float* __restrict__ W0, u16* __restrict__ dst) {
    __shared__ u16 sT[64*68];
    int bid = blockIdx.x;
    int mat = bid / 96, rem = bid % 96;
    int kt = rem / 16, nt = rem % 16;
    int i = mat / 4 + 1, o = mat % 4;
    const float* src = W0 + (size_t)(i*5 + o) * IN_DIM * HIDDEN;
    int t = threadIdx.x;
    #pragma unroll
    for (int p = 0; p < 16; ++p) {
        int e = p*256 + t;
        int kr = e >> 6, nc = e & 63;
        int k = kt*64 + kr;
        float v = (k < IN_DIM) ? src[(size_t)k*HIDDEN + nt*64 + nc] : 0.f;
        f16 h = (f16)v;
        sT[nc*68 + kr] = __builtin_bit_cast(u16, h);
    }
    __syncthreads();
    u16* d = dst + (size_t)mat * HIDDEN * KPAD0;
    #pragma unroll
    for (int p = 0; p < 4; ++p) {
        int c = p*256 + t;
        int nc = c >> 4, k4 = (c & 15) * 4;
        u16x4 v;
        #pragma unroll
        for (int j = 0; j < 4; ++j) v[j] = sT[nc*68 + k4 + j];
        *(u16x4*)&d[(size_t)(nt*64 + nc)*KPAD0 + kt*64 + k4] = v;
    }
}

// ---------------- Wh used slices -> transposed f16 [1024][1024] ----------------
__global__ void wtransH_kernel(const float* __restrict__ Wh, u16* __restrict__ dst) {
    const int SK[10] = {1,1,1,1,2,2,2,3,3,4};
    const int SI[10] = {2,3,4,5,3,4,5,4,5,5};
    __shared__ u16 sT[64*68];
    int bid = blockIdx.x;
    int mat = bid >> 8, rem = bid & 255;
    int kt = rem / 16, nt = rem % 16;
    int e = mat / 4, o = mat % 4;
    const float* src = Wh + (size_t)(((SK[e]-1)*6 + SI[e])*5 + o) * HIDDEN * HIDDEN;
    int t = threadIdx.x;
    #pragma unroll
    for (int p = 0; p < 16; ++p) {
        int ee = p*256 + t;
        int kr = ee >> 6, nc = ee & 63;
        float v = src[(size_t)(kt*64 + kr)*HIDDEN + nt*64 + nc];
        f16 h = (f16)v;
        sT[nc*68 + kr] = __builtin_bit_cast(u16, h);
    }
    __syncthreads();
    u16* d = dst + (size_t)mat * HIDDEN * HIDDEN;
    #pragma unroll
    for (int p = 0; p < 4; ++p) {
        int c = p*256 + t;
        int nc = c >> 4, k4 = (c & 15) * 4;
        u16x4 v;
        #pragma unroll
        for (int j = 0; j < 4; ++j) v[j] = sT[nc*68 + k4 + j];
        *(u16x4*)&d[(size_t)(nt*64 + nc)*HIDDEN + kt*64 + k4] = v;
    }
}

// ---------------- zero the 5 f32 accumulator buffers ----------------
__global__ void zero_kernel(float* __restrict__ p) {
    int idx = blockIdx.x * 256 + threadIdx.x;
    *(f32x4*)&p[(size_t)idx*4] = (f32x4){0.f, 0.f, 0.f, 0.f};
}

// ---------------- f32 acc -> f16 for next step's A ----------------
__global__ void cvt_kernel(const float* __restrict__ src, u16* __restrict__ dst) {
    int idx = blockIdx.x * 256 + threadIdx.x;
    f32x4 v = *(const f32x4*)&src[(size_t)idx*4];
    u16x4 h;
    #pragma unroll
    for (int j = 0; j < 4; ++j) { f16 x = (f16)v[j]; h[j] = __builtin_bit_cast(u16, x); }
    *(u16x4*)&dst[(size_t)idx*4] = h;
}

// ---------------- one DAG edge-tile: accf32_i += sum_o z*act_o(in_k @ W + b) ----------------
// 1-D grid, XCD-swizzled: slot=bid&7 (XCD), m=(bid>>3)&31, e=(bid>>8)*8+slot -> (edge, n-tile).
// All 32 m-blocks of one (edge,n) run consecutively on ONE XCD -> B-tile stays in that L2.
__global__ __launch_bounds__(256)
void step_kernel(int stepi,
                 const u16* __restrict__ x16, const u16* __restrict__ acc16,
                 float* __restrict__ accf,
                 const u16* __restrict__ w0t, const u16* __restrict__ wht,
                 const float* __restrict__ b0, const float* __restrict__ bh,
                 const float* __restrict__ zws) {
    __shared__ alignas(16) u16 sA[64*64];
    __shared__ alignas(16) u16 sB[4][64*64];
    const int t = threadIdx.x;
    const int lane = t & 63, wid = t >> 6;
    const int l15 = lane & 15, lk = lane >> 4;

    const int bid  = blockIdx.x;
    const int slot = bid & 7;
    const int q    = bid >> 3;
    const int m0   = (q & 31) * 64;
    const int e    = (q >> 5) * 8 + slot;   // e in [0, 16*stepi)
    const int k    = e >> 4;                 // edge source node index 0..stepi-1
    const int n0   = (e & 15) * 64;

    const u16* Ap; int ldA, nks;
    const u16* Wt; int ldW;
    const float* bias;
    if (k == 0) {
        Ap = x16; ldA = KPAD0; nks = KPAD0/64;
        Wt = w0t + (size_t)((stepi-1)*4) * HIDDEN * KPAD0; ldW = KPAD0;
        bias = b0 + (size_t)(stepi*5) * HIDDEN;
    } else {
        Ap = acc16 + (size_t)(k-1) * BATCH * HIDDEN; ldA = HIDDEN; nks = HIDDEN/64;
        int eidx = D_PREF[k] + (stepi - k - 1);
        Wt = wht + (size_t)(eidx*4) * HIDDEN * HIDDEN; ldW = HIDDEN;
        bias = bh + (size_t)(((k-1)*6 + stepi)*5) * HIDDEN;
    }
    const float* zp = zws + (k*6 + stepi)*5;

    // staging lane geometry: lane L -> row_in_chunk = L>>3, LDS slot = L&7,
    // fetch global chunk sc = (L&7) ^ (L>>3)   (XOR swizzle for conflict-free reads)
    const int srow = lane >> 3;
    const int sc   = (lane & 7) ^ srow;

    const u16* aG0 = Ap + (size_t)(m0 + wid*16 + srow)     * ldA + sc*8;
    const u16* aG1 = Ap + (size_t)(m0 + wid*16 + 8 + srow) * ldA + sc*8;
    u16* aL0 = &sA[(wid*2)   * 512];
    u16* aL1 = &sA[(wid*2+1) * 512];
    const u16* Wop = Wt + (size_t)wid * HIDDEN * ldW;
    const u16* bG[8];
    #pragma unroll
    for (int p = 0; p < 8; ++p)
        bG[p] = Wop + (size_t)(n0 + p*8 + srow) * ldW + sc*8;
    u16* bL = &sB[wid][0];

    f32x4 acc[4][4] = {};   // [mfrag][op]

    for (int kb = 0; kb < nks; ++kb) {
        const int koff = kb * 64;
        gll16(aG0 + koff, aL0);
        gll16(aG1 + koff, aL1);
        #pragma unroll
        for (int p = 0; p < 8; ++p)
            gll16(bG[p] + koff, bL + p*512);
        __syncthreads();
        #pragma unroll
        for (int kc = 0; kc < 2; ++kc) {
            f16x8 af[4], bf[4];
            #pragma unroll
            for (int f = 0; f < 4; ++f) {
                int row = f*16 + l15;
                int cc = (kc*4 + lk) ^ (row & 7);
                af[f] = *(const f16x8*)&sA[row*64 + cc*8];
            }
            #pragma unroll
            for (int o = 0; o < 4; ++o) {
                int row = wid*16 + l15;
                int cc = (kc*4 + lk) ^ (row & 7);
                bf[o] = *(const f16x8*)&sB[o][row*64 + cc*8];
            }
            #pragma unroll
            for (int o = 0; o < 4; ++o)
                #pragma unroll
                for (int f = 0; f < 4; ++f)
                    acc[f][o] = __builtin_amdgcn_mfma_f32_16x16x32_f16(af[f], bf[o], acc[f][o], 0, 0, 0);
        }
        __syncthreads();
    }

    // epilogue: bias + activation + z-mix (in-register), one atomicAdd per element
    const int colw = n0 + wid*16 + l15;
    float outv[4][4] = {};
    #pragma unroll
    for (int o = 0; o < 4; ++o) {
        float zv = zp[o];
        float bv = bias[(size_t)o*HIDDEN + colw];
        #pragma unroll
        for (int f = 0; f < 4; ++f)
            #pragma unroll
            for (int r = 0; r < 4; ++r) {
                float pre = acc[f][o][r] + bv;
                float a;
                if      (o == 0) a = tanhf(pre);
                else if (o == 1) a = fmaxf(pre, 0.f);
                else if (o == 2) a = (pre > 0.f) ? pre : expm1f(pre);
                else             a = (pre > 0.f) ? pre : 0.01f * pre;
                outv[f][r] += zv * a;
            }
    }
    #pragma unroll
    for (int f = 0; f < 4; ++f)
        #pragma unroll
        for (int r = 0; r < 4; ++r)
            atomicAdd(&accf[(size_t)(m0 + f*16 + lk*4 + r)*HIDDEN + colw], outv[f][r]);
}

// ---------------- out = tanh(acc5_f32 @ Wout + bout) ----------------
__global__ void out_kernel(const float* __restrict__ acc5, const float* __restrict__ Wout,
                           const float* __restrict__ bout, float* __restrict__ out) {
    int t = threadIdx.x;
    int g = t & 15, rl = t >> 4;
    int row = blockIdx.x * 16 + rl;
    const float* a = acc5 + (size_t)row * HIDDEN;
    float s[OUT_DIM] = {};
    for (int kk = 0; kk < HIDDEN/16; ++kk) {
        int kidx = kk*16 + g;
        float av = a[kidx];
        const float* wr = Wout + (size_t)kidx * OUT_DIM;
        #pragma unroll
        for (int j = 0; j < OUT_DIM; ++j) s[j] += av * wr[j];
    }
    #pragma unroll
    for (int m = 1; m < 16; m <<= 1) {
        #pragma unroll
        for (int j = 0; j < OUT_DIM; ++j) s[j] += __shfl_xor(s[j], m, 64);
    }
    if (g == 0) {
        #pragma unroll
        for (int j = 0; j < OUT_DIM; ++j)
            out[(size_t)row*OUT_DIM + j] = tanhf(s[j] + bout[j]);
    }
}

extern "C" void kernel_launch(void* const* d_in, const int* in_sizes, int n_in,
                              void* d_out, int out_size, void* d_ws, size_t ws_size,
                              hipStream_t stream) {
    const float* x    = (const float*)d_in[0];
    const float* W0   = (const float*)d_in[1];
    const float* b0   = (const float*)d_in[2];
    const float* Wh   = (const float*)d_in[3];
    const float* bh   = (const float*)d_in[4];
    const float* Wout = (const float*)d_in[5];
    const float* bout = (const float*)d_in[6];
    const float* la   = (const float*)d_in[7];
    const float* eps  = (const float*)d_in[8];
    float* out = (float*)d_out;

    char* ws = (char*)d_ws;
    float* zws  = (float*)(ws + WS_Z);
    u16* x16    = (u16*)(ws + WS_X16);
    u16* acc16  = (u16*)(ws + WS_ACC16);
    float* accf = (float*)(ws + WS_ACCF);
    u16* w0t    = (u16*)(ws + WS_W0T);
    u16* wht    = (u16*)(ws + WS_WHT);

    z_kernel<<<1, 32, 0, stream>>>(la, eps, zws);
    xcvt_kernel<<<(BATCH*KPAD0)/256, 256, 0, stream>>>(x, x16);
    wtrans0_kernel<<<1920, 256, 0, stream>>>(W0, w0t);
    wtransH_kernel<<<10240, 256, 0, stream>>>(Wh, wht);
    zero_kernel<<<(5*BATCH*HIDDEN)/(4*256), 256, 0, stream>>>(accf);

    for (int i = 1; i <= 5; ++i) {
        float* accf_i = accf + (size_t)(i-1)*BATCH*HIDDEN;
        step_kernel<<<512*i, 256, 0, stream>>>(
            i, x16, acc16, accf_i, w0t, wht, b0, bh, zws);
        if (i < 5)
            cvt_kernel<<<(BATCH*HIDDEN)/(4*256), 256, 0, stream>>>(
                accf_i, acc16 + (size_t)(i-1)*BATCH*HIDDEN);
    }
    out_kernel<<<BATCH/16, 256, 0, stream>>>(accf + (size_t)4*BATCH*HIDDEN, Wout, bout, out);
}